// Round 19
// baseline (133.177 us; speedup 1.0000x reference)
//
#include <hip/hip_runtime.h>

// SignSemanticsAggregator on MI355X (gfx950), round 19.
// E = sp + 32*sn (i8); E@E digits: M_same=(acc&31)+(acc>>10), M_diff=(acc>>5)&31.
// Round-19: 256x256 tiles. Grid = 256 blocks (= CU count, all co-resident,
// no tail): 136 HEAVY (upper-tri GEMM tiles, R18 drain schedule, BK=128,
// 32 phases, 2x64KB LDS dbuf, 8 waves of 128x64) + 120 LIGHT (strictly-lower
// mirror-xor tiles on otherwise-idle CUs). Tiles partition 4096^2 exactly.

#define NN 4096
#define NW 128
#define MASK_BYTES ((size_t)NN * NW * 4)     // 2 MiB per mask
#define MASK_WORDS ((size_t)NN * NW)

typedef unsigned int u32;
typedef __attribute__((ext_vector_type(4))) int int4v;
typedef __attribute__((ext_vector_type(4))) float f32x4;

__device__ __forceinline__ void gload_lds16(const char* g, char* l) {
    __builtin_amdgcn_global_load_lds(
        (const __attribute__((address_space(1))) void*)g,
        (__attribute__((address_space(3))) void*)l, 16, 0, 0);
}

// ---------------- preprocessing ----------------

__global__ void zero_ws(int4v* __restrict__ p) {
    p[blockIdx.x * 256 + threadIdx.x] = int4v{0, 0, 0, 0};   // 8 MiB
}

__global__ void scatter_all(const int* __restrict__ e0, const int* __restrict__ e1,
                            const int* __restrict__ e2, const int* __restrict__ e3,
                            int E0, int E1, int E2, int E3,
                            u32* __restrict__ ws) {
    int i = blockIdx.x * blockDim.x + threadIdx.x;
    u32* Pt = ws + 0 * MASK_WORDS;
    u32* P1 = ws + 1 * MASK_WORDS;
    u32* Nt = ws + 2 * MASK_WORDS;
    u32* N1 = ws + 3 * MASK_WORDS;
    if (i < E0) { int r = e0[i], c = e0[i + E0];
        atomicOr(&Pt[r * NW + (c >> 5)], 1u << (c & 31)); }
    if (i < E1) { int r = e1[i], c = e1[i + E1];
        atomicOr(&P1[r * NW + (c >> 5)], 1u << (c & 31)); }
    if (i < E2) { int r = e2[i], c = e2[i + E2];
        atomicOr(&Nt[r * NW + (c >> 5)], 1u << (c & 31)); }
    if (i < E3) { int r = e3[i], c = e3[i + E3];
        atomicOr(&N1[r * NW + (c >> 5)], 1u << (c & 31)); }
}

// Expand 16 mask bits (sp, sn) -> 16 i8 of E = sp + 32*sn.
__device__ __forceinline__ int4v expand_e(u32 sp, u32 sn) {
    int4v E;
    #pragma unroll
    for (int i = 0; i < 4; i++) {
        u32 p = (((sp >> (4 * i)) & 0xFu) * 0x00204081u) & 0x01010101u;
        u32 n = (((sn >> (4 * i)) & 0xFu) * 0x00204081u) & 0x01010101u;
        E[i] = (int)(p | (n << 5));
    }
    return E;
}

// Blocks [0,2048): E row-wise from P1/N1. Blocks [2048,4096): ET via in-wave
// ballot bit-transpose. Pos-priority and diagonal clearing in both halves.
__global__ void build_both(const u32* __restrict__ masks,
                           char* __restrict__ E, char* __restrict__ ET) {
    const u32* P  = masks + 1 * MASK_WORDS;
    const u32* Nm = masks + 3 * MASK_WORDS;
    if (blockIdx.x < 2048) {
        int w = blockIdx.x * 256 + threadIdx.x;      // word index a*128 + col
        u32 p = P[w];
        u32 n = Nm[w] & ~p;
        int a = w >> 7, col = w & 127;
        if ((a >> 5) == col) {
            u32 db = 1u << (a & 31);
            p &= ~db; n &= ~db;
        }
        char* dst = E + (size_t)a * NN + col * 32;
        *reinterpret_cast<int4v*>(dst)      = expand_e(p & 0xFFFFu, n & 0xFFFFu);
        *reinterpret_cast<int4v*>(dst + 16) = expand_e(p >> 16, n >> 16);
    } else {
        int gw = (blockIdx.x - 2048) * 4 + (threadIdx.x >> 6);  // 8192 waves
        int lane = threadIdx.x & 63;
        int ab = gw >> 7;        // 64-row block of a
        int wc = gw & 127;       // word column (c-block of 32)
        u32 pw = P[(ab * 64 + lane) * NW + wc];
        u32 nw = Nm[(ab * 64 + lane) * NW + wc];
        u32 myp = 0, myn = 0;
        #pragma unroll
        for (int j = 0; j < 32; j++) {
            unsigned long long bp = __ballot((pw >> j) & 1u);
            unsigned long long bn = __ballot((nw >> j) & 1u);
            if ((lane & 31) == j) {
                myp = (lane < 32) ? (u32)bp : (u32)(bp >> 32);
                myn = (lane < 32) ? (u32)bn : (u32)(bn >> 32);
            }
        }
        u32 p = myp;
        u32 n = myn & ~p;
        int c = wc * 32 + (lane & 31);
        int abase = ab * 64 + (lane >> 5) * 32;
        if (c >= abase && c < abase + 32) {          // clear diagonal a == c
            u32 db = 1u << (c - abase);
            p &= ~db; n &= ~db;
        }
        char* dst = ET + (size_t)c * NN + abase;
        *reinterpret_cast<int4v*>(dst)      = expand_e(p & 0xFFFFu, n & 0xFFFFu);
        *reinterpret_cast<int4v*>(dst + 16) = expand_e(p >> 16, n >> 16);
    }
}

// ---------------- fused GEMM + epilogue ----------------
// Grid = 256 blocks of 512 threads. id<136: heavy upper-tri 256^2 GEMM tile
// (BK=128, 32 phases, 2x64KB dbuf, 8 waves each 128x64). id>=136: light
// strictly-lower 256^2 mirror-xor tile.
__global__ __launch_bounds__(512, 1) void gemm_ep(
    const char* __restrict__ E, const char* __restrict__ ET,
    const u32* __restrict__ Pt, const u32* __restrict__ P1,
    const u32* __restrict__ Nt, const u32* __restrict__ N1,
    float* __restrict__ out)
{
    const int tid = threadIdx.x;
    const size_t plane = (size_t)NN * NN;

    // bijective XCD swizzle over 256 blocks (256 = 8 * 32)
    const int id = ((int)blockIdx.x & 7) * 32 + ((int)blockIdx.x >> 3);

    if (id >= 136) {
        // ---- LIGHT: strictly-lower 256x256 mirror-xor tile ----
        int j = id - 136;                    // 0..119
        int R = 1;
        while ((R + 1) * R / 2 <= j) ++R;    // row R has R tiles (C < R)
        int C = j - R * (R - 1) / 2;
        const int r0 = R << 8, c0l = C << 8;
        #pragma unroll 4
        for (int pass = 0; pass < 32; ++pass) {
            int e = pass * 2048 + tid * 4;   // element in 256x256 tile
            int r = e >> 8, cc = e & 255;
            int widx = (r0 + r) * NW + ((c0l + cc) >> 5);
            int sh = cc & 31;
            u32 xp = (P1[widx] ^ Pt[widx]) >> sh;
            u32 xn = (N1[widx] ^ Nt[widx]) >> sh;
            f32x4 o0, o1;
            #pragma unroll
            for (int i = 0; i < 4; i++) {
                o0[i] = (float)((xp >> i) & 1u);
                o1[i] = (float)((xn >> i) & 1u);
            }
            size_t ob = (size_t)(r0 + r) * NN + c0l + cc;
            *reinterpret_cast<f32x4*>(out + ob) = o0;
            *reinterpret_cast<f32x4*>(out + plane + ob) = o1;
        }
        return;
    }

    // ---- HEAVY: upper-tri (incl diag) 256x256 GEMM tile ----
    int by = 0;
    while (16 * (by + 1) - ((by + 1) * by) / 2 <= id) ++by;
    int bx = by + id - (16 * by - (by * (by - 1)) / 2);
    const int a0 = by << 8, c0 = bx << 8;

    __shared__ char LB[2][2][32768];   // [buf][A/B][row*128 + slot*16], 128 KB

    const int wave = tid >> 6, lane = tid & 63;
    const int wr = (wave >> 2) * 128;        // 2 wave-rows of 128
    const int wcol = (wave & 3) * 64;        // 4 wave-cols of 64
    const int lr = lane & 15, lg = lane >> 4;

    // Staging: instr g covers LDS [g*8192 + tid*16] = row (g*64 + tid>>3),
    // slot (tid&7). Source chunk = slot ^ (row&7); (row&7) == (tid>>3)&7.
    const int soff = (((tid & 7) ^ ((tid >> 3) & 7)) << 4);
    const char* gA = E  + (size_t)(a0 + (tid >> 3)) * NN + soff;
    const char* gB = ET + (size_t)(c0 + (tid >> 3)) * NN + soff;
    const int t16 = tid * 16;

    int4v acc[8][4];
    int4v zero = {0, 0, 0, 0};
    #pragma unroll
    for (int m = 0; m < 8; m++)
        #pragma unroll
        for (int n = 0; n < 4; n++) acc[m][n] = zero;

    #define STAGE(b, p)                                                     \
        do {                                                                \
            const size_t koff = (size_t)(p) * 128;                          \
            _Pragma("unroll")                                               \
            for (int g = 0; g < 4; g++) {                                   \
                gload_lds16(gA + (size_t)g * 64 * NN + koff,                \
                            &LB[b][0][g * 8192 + t16]);                     \
                gload_lds16(gB + (size_t)g * 64 * NN + koff,                \
                            &LB[b][1][g * 8192 + t16]);                     \
            }                                                               \
        } while (0)

    #define COMPUTE(b)                                                          \
        do {                                                                    \
            _Pragma("unroll")                                                   \
            for (int ks = 0; ks < 2; ks++) {                                    \
                int4v bf[4];                                                    \
                _Pragma("unroll")                                               \
                for (int n = 0; n < 4; n++) {                                   \
                    int rowb = wcol + n * 16 + lr;                              \
                    bf[n] = *reinterpret_cast<const int4v*>(&LB[b][1][          \
                        rowb * 128 + (((ks * 4 + lg) ^ (rowb & 7)) << 4)]);     \
                }                                                               \
                __builtin_amdgcn_s_setprio(1);                                  \
                _Pragma("unroll")                                               \
                for (int m = 0; m < 8; m++) {                                   \
                    int rowa = wr + m * 16 + lr;                                \
                    int4v af = *reinterpret_cast<const int4v*>(&LB[b][0][       \
                        rowa * 128 + (((ks * 4 + lg) ^ (rowa & 7)) << 4)]);     \
                    _Pragma("unroll")                                           \
                    for (int n = 0; n < 4; n++)                                 \
                        acc[m][n] = __builtin_amdgcn_mfma_i32_16x16x64_i8(      \
                            af, bf[n], acc[m][n], 0, 0, 0);                     \
                }                                                               \
                __builtin_amdgcn_s_setprio(0);                                  \
            }                                                                   \
        } while (0)

    // prologue: stage phase 0, drain (8 staging loads)
    STAGE(0, 0);
    asm volatile("s_waitcnt vmcnt(0)" ::: "memory");
    __builtin_amdgcn_s_barrier();

    int cur = 0;
    for (int p = 0; p < 31; ++p) {
        STAGE(cur ^ 1, p + 1);               // 8 loads for next phase
        COMPUTE(cur);                        // 24 ds_read + 64 MFMA
        asm volatile("s_waitcnt vmcnt(0)" ::: "memory");   // next buf staged
        __builtin_amdgcn_s_barrier();
        cur ^= 1;
    }
    COMPUTE(cur);                            // p = 31
    #undef STAGE
    #undef COMPUTE

    // ---- fused epilogue: C/D layout col=lane&15, row=(lane>>4)*4+q ----
    #pragma unroll
    for (int m = 0; m < 8; m++) {
        #pragma unroll
        for (int n = 0; n < 4; n++) {
            #pragma unroll
            for (int q = 0; q < 4; q++) {
                int a = a0 + wr + m * 16 + lg * 4 + q;
                int c = c0 + wcol + n * 16 + lr;
                int widx = a * NW + (c >> 5);
                int bit = c & 31;
                u32 p1 = (P1[widx] >> bit) & 1u;
                u32 n1 = (N1[widx] >> bit) & 1u;
                u32 pt = (Pt[widx] >> bit) & 1u;
                u32 nt = (Nt[widx] >> bit) & 1u;
                int av = acc[m][n][q];
                int Ms = (av & 31) + (av >> 10);     // d0 + d2
                int Md = (av >> 5) & 31;             // d1
                int o0 = (int)(pt ^ p1) + ((a < c && !p1) ? Ms : 0);
                int o1 = (int)(nt ^ n1) + ((a < c && !n1) ? Md : 0);
                size_t oi = (size_t)a * NN + c;
                out[oi] = (float)o0;
                out[plane + oi] = (float)o1;
            }
        }
    }
}

extern "C" void kernel_launch(void* const* d_in, const int* in_sizes, int n_in,
                              void* d_out, int out_size, void* d_ws, size_t ws_size,
                              hipStream_t stream) {
    char* ws = (char*)d_ws;
    u32* masks = (u32*)ws;                    // Pt,P1,Nt,N1 (4 x 2 MiB)
    u32* Pt = masks + 0 * MASK_WORDS;
    u32* P1 = masks + 1 * MASK_WORDS;
    u32* Nt = masks + 2 * MASK_WORDS;
    u32* N1 = masks + 3 * MASK_WORDS;
    char* E  = ws + 4 * MASK_BYTES;           // 16 MiB, linear
    char* ET = E + (size_t)NN * NN;           // 16 MiB, linear
    // ws use: 8 MiB masks + 32 MiB E/ET = 40 MiB

    zero_ws<<<2048, 256, 0, stream>>>((int4v*)masks);   // 8 MiB, ~2 us

    // input order: A_pos_t, A_pos_tp1, A_neg_t, A_neg_tp1
    int E0 = in_sizes[0] / 2, E1 = in_sizes[1] / 2;
    int E2 = in_sizes[2] / 2, E3 = in_sizes[3] / 2;
    int Emax = max(max(E0, E1), max(E2, E3));
    scatter_all<<<(Emax + 255) / 256, 256, 0, stream>>>(
        (const int*)d_in[0], (const int*)d_in[1], (const int*)d_in[2],
        (const int*)d_in[3], E0, E1, E2, E3, masks);

    build_both<<<4096, 256, 0, stream>>>(masks, E, ET);

    gemm_ep<<<256, 512, 0, stream>>>(E, ET, Pt, P1, Nt, N1, (float*)d_out);
}